// Round 1
// baseline (513.143 us; speedup 1.0000x reference)
//
#include <hip/hip_runtime.h>

typedef unsigned short u16;
typedef __attribute__((ext_vector_type(8))) short bf16x8;
typedef __attribute__((ext_vector_type(4))) float f32x4;
typedef __attribute__((ext_vector_type(4))) unsigned short u16x4;

#define NB 4
#define NS 2048
#define DIN 1024
#define DM 1024
#define NH 16
#define HD 64

__device__ __forceinline__ u16 f2bf(float f) {
  union { float f; unsigned u; } x; x.f = f;
  unsigned r = x.u + 0x7fffu + ((x.u >> 16) & 1u);
  return (u16)(r >> 16);
}

__device__ __forceinline__ void gl_lds16(const u16* g, u16* l) {
  __builtin_amdgcn_global_load_lds((const __attribute__((address_space(1))) void*)g,
                                   (__attribute__((address_space(3))) void*)l, 16, 0, 0);
}

// ---------------- fp32 -> bf16 convert (grid-stride, float4) ----------------
__global__ void cvt_kernel(const float* __restrict__ src, u16* __restrict__ dst, int n4) {
  int stride = gridDim.x * blockDim.x;
  for (int i = blockIdx.x * blockDim.x + threadIdx.x; i < n4; i += stride) {
    f32x4 v = ((const f32x4*)src)[i];
    u16x4 o = { f2bf(v.x), f2bf(v.y), f2bf(v.z), f2bf(v.w) };
    ((u16x4*)dst)[i] = o;
  }
}

// ---------------- W [K][N] fp32 -> Wt [N][K] bf16 (LDS tiled) ----------------
__global__ void wtrans_kernel(const float* __restrict__ W, u16* __restrict__ Wt) {
  __shared__ float tile[64][65];
  int n0 = blockIdx.x * 64, k0 = blockIdx.y * 64;
  int t = threadIdx.x;
#pragma unroll
  for (int i = 0; i < 16; i++) {
    int idx = t + i * 256;
    int r = idx >> 6, c = idx & 63;
    tile[r][c] = W[(size_t)(k0 + r) * DM + n0 + c];
  }
  __syncthreads();
#pragma unroll
  for (int i = 0; i < 16; i++) {
    int idx = t + i * 256;
    int r = idx >> 6, c = idx & 63;  // r = n-local, c = k-local
    Wt[(size_t)(n0 + r) * DIN + k0 + c] = f2bf(tile[c][r]);
  }
}

// ---------------- projection GEMM: out[m][n] = X[m][:] . Wt[n][:] + bias ----
// 128x128 tile, BK=64, global_load_lds width=16, 16x16x32 bf16 MFMA.
// Stores bf16 into [b, h, s, d] layout.
__global__ __launch_bounds__(256) void proj_kernel(
    const u16* __restrict__ Xq, const u16* __restrict__ Xk, const u16* __restrict__ Xv,
    const u16* __restrict__ Wtq, const u16* __restrict__ Wtk, const u16* __restrict__ Wtv,
    const float* __restrict__ bq, const float* __restrict__ bk, const float* __restrict__ bv,
    u16* __restrict__ oq, u16* __restrict__ ok, u16* __restrict__ ov) {
  __shared__ __align__(16) u16 Abuf[128 * 64];
  __shared__ __align__(16) u16 Bbuf[128 * 64];
  const int z = blockIdx.z;
  const u16* X  = z == 0 ? Xq : z == 1 ? Xk : Xv;
  const u16* Wt = z == 0 ? Wtq : z == 1 ? Wtk : Wtv;
  const float* bias = z == 0 ? bq : z == 1 ? bk : bv;
  u16* out = z == 0 ? oq : z == 1 ? ok : ov;
  const int m0 = blockIdx.y * 128, n0 = blockIdx.x * 128;
  const int t = threadIdx.x, lane = t & 63, w = t >> 6;
  const int wm = (w >> 1) * 64, wn = (w & 1) * 64;
  f32x4 acc[4][4] = {};
  for (int k0 = 0; k0 < DIN; k0 += 64) {
#pragma unroll
    for (int i = 0; i < 4; i++) {
      int idx = (w * 4 + i) * 64 + lane;        // 16B-chunk id, 8 chunks per row
      int row = idx >> 3, kc = idx & 7;
      gl_lds16(&X [(size_t)(m0 + row) * DIN + k0 + kc * 8], &Abuf[(w * 4 + i) * 512]);
      gl_lds16(&Wt[(size_t)(n0 + row) * DIN + k0 + kc * 8], &Bbuf[(w * 4 + i) * 512]);
    }
    __syncthreads();   // drains vmcnt for global_load_lds
#pragma unroll
    for (int ks = 0; ks < 2; ks++) {
      bf16x8 af[4], bfr[4];
#pragma unroll
      for (int i = 0; i < 4; i++)
        af[i]  = *(const bf16x8*)&Abuf[(wm + i * 16 + (lane & 15)) * 64 + ks * 32 + (lane >> 4) * 8];
#pragma unroll
      for (int j = 0; j < 4; j++)
        bfr[j] = *(const bf16x8*)&Bbuf[(wn + j * 16 + (lane & 15)) * 64 + ks * 32 + (lane >> 4) * 8];
#pragma unroll
      for (int i = 0; i < 4; i++)
#pragma unroll
        for (int j = 0; j < 4; j++)
          acc[i][j] = __builtin_amdgcn_mfma_f32_16x16x32_bf16(af[i], bfr[j], acc[i][j], 0, 0, 0);
    }
    __syncthreads();
  }
  // epilogue: + bias, cvt bf16, scatter to [b,h,s,d]
#pragma unroll
  for (int j = 0; j < 4; j++) {
    int n = n0 + wn + j * 16 + (lane & 15);
    float bias_v = bias[n];
    int h = n >> 6, d = n & 63;
#pragma unroll
    for (int i = 0; i < 4; i++) {
#pragma unroll
      for (int r = 0; r < 4; r++) {
        int m = m0 + wm + i * 16 + (lane >> 4) * 4 + r;  // C/D: row=(lane>>4)*4+reg
        int b = m >> 11, s = m & 2047;
        out[((size_t)(b * NH + h) * NS + s) * HD + d] = f2bf(acc[i][j][r] + bias_v);
      }
    }
  }
}

// ---------------- per-head V [s][d] -> vT [d][s] (bf16) ---------------------
__global__ void vtrans_kernel(const u16* __restrict__ v, u16* __restrict__ vT) {
  __shared__ __align__(16) u16 tile[64 * 72];
  int bh = blockIdx.y;
  int s0 = blockIdx.x * 64;
  const u16* src = v + ((size_t)bh * NS + s0) * HD;
  int t = threadIdx.x;
#pragma unroll
  for (int it = 0; it < 2; it++) {
    int e = (t + it * 256) * 8;
    int s = e >> 6, d0 = e & 63;
    *(bf16x8*)&tile[s * 72 + d0] = *(const bf16x8*)&src[e];
  }
  __syncthreads();
  u16* dst = vT + (size_t)bh * HD * NS + s0;
#pragma unroll
  for (int it = 0; it < 2; it++) {
    int c = t + it * 256;
    int d = c >> 3, sc = (c & 7) * 8;
    bf16x8 tv;
#pragma unroll
    for (int j = 0; j < 8; j++) tv[j] = (short)tile[(sc + j) * 72 + d];
    *(bf16x8*)&dst[(size_t)d * NS + sc] = tv;
  }
}

// ---------------- flash attention: one block per (b*h, 64 q rows) -----------
__global__ __launch_bounds__(256) void attn_kernel(
    const u16* __restrict__ q, const u16* __restrict__ k, const u16* __restrict__ vT,
    float* __restrict__ out) {
  __shared__ __align__(16) u16 qt[64 * 72];
  __shared__ __align__(16) u16 kt[64 * 72];
  __shared__ __align__(16) u16 vt[64 * 72];
  __shared__ __align__(16) u16 pt[4 * 16 * 72];
  const int bh = blockIdx.y;
  const int q0 = blockIdx.x * 64;
  const int t = threadIdx.x, lane = t & 63, w = t >> 6;
  const u16* qsrc = q  + ((size_t)bh * NS + q0) * HD;
  const u16* ksrc = k  + (size_t)bh * NS * HD;
  const u16* vsrc = vT + (size_t)bh * HD * NS;
  // stage q tile [64][72]
#pragma unroll
  for (int it = 0; it < 2; it++) {
    int e = (t + it * 256) * 8;
    int r = e >> 6, d0 = e & 63;
    *(bf16x8*)&qt[r * 72 + d0] = *(const bf16x8*)&qsrc[e];
  }
  f32x4 o[4] = {};
  float mrow[4], lrow[4];
#pragma unroll
  for (int r = 0; r < 4; r++) { mrow[r] = -1e30f; lrow[r] = 0.f; }
  const int e0 = t * 8, e1 = (t + 256) * 8;
  for (int kt0 = 0; kt0 < NS; kt0 += 64) {
    // prefetch staging data into registers (overlaps prior-iter tail)
    bf16x8 kreg0 = *(const bf16x8*)&ksrc[(size_t)kt0 * HD + e0];
    bf16x8 kreg1 = *(const bf16x8*)&ksrc[(size_t)kt0 * HD + e1];
    bf16x8 vreg0 = *(const bf16x8*)&vsrc[(size_t)(t >> 3) * NS + kt0 + (t & 7) * 8];
    bf16x8 vreg1 = *(const bf16x8*)&vsrc[(size_t)((t + 256) >> 3) * NS + kt0 + (t & 7) * 8];
    __syncthreads();  // (a) prior-iter LDS reads done (also covers qt visibility via (b))
    *(bf16x8*)&kt[(e0 >> 6) * 72 + (e0 & 63)] = kreg0;
    *(bf16x8*)&kt[(e1 >> 6) * 72 + (e1 & 63)] = kreg1;
    *(bf16x8*)&vt[(t >> 3) * 72 + (t & 7) * 8] = vreg0;
    *(bf16x8*)&vt[((t + 256) >> 3) * 72 + (t & 7) * 8] = vreg1;
    __syncthreads();  // (b) tiles ready
    // S = q @ k^T, wave owns q rows w*16..w*16+15, all 64 keys
    f32x4 sacc[4] = {};
#pragma unroll
    for (int ks = 0; ks < 2; ks++) {
      bf16x8 aq = *(const bf16x8*)&qt[(w * 16 + (lane & 15)) * 72 + ks * 32 + (lane >> 4) * 8];
#pragma unroll
      for (int j = 0; j < 4; j++) {
        bf16x8 bk = *(const bf16x8*)&kt[(j * 16 + (lane & 15)) * 72 + ks * 32 + (lane >> 4) * 8];
        sacc[j] = __builtin_amdgcn_mfma_f32_16x16x32_bf16(aq, bk, sacc[j], 0, 0, 0);
      }
    }
    // online softmax, wave-local (rows live in 16-lane groups)
#pragma unroll
    for (int r = 0; r < 4; r++) {
      float sv[4];
      float mx = mrow[r];
#pragma unroll
      for (int j = 0; j < 4; j++) { sv[j] = sacc[j][r] * 0.125f; mx = fmaxf(mx, sv[j]); }
#pragma unroll
      for (int msk = 1; msk <= 8; msk <<= 1) mx = fmaxf(mx, __shfl_xor(mx, msk));
      float alpha = exp2f((mrow[r] - mx) * 1.44269504f);
      float ls = 0.f;
#pragma unroll
      for (int j = 0; j < 4; j++) {
        float p = exp2f((sv[j] - mx) * 1.44269504f);
        ls += p;
        pt[(w * 16 + (lane >> 4) * 4 + r) * 72 + j * 16 + (lane & 15)] = f2bf(p);
      }
#pragma unroll
      for (int msk = 1; msk <= 8; msk <<= 1) ls += __shfl_xor(ls, msk);
      lrow[r] = lrow[r] * alpha + ls;
      mrow[r] = mx;
#pragma unroll
      for (int j = 0; j < 4; j++) o[j][r] *= alpha;
    }
    __syncthreads();  // (c) P visible
    // O += P @ Vtile
#pragma unroll
    for (int ks = 0; ks < 2; ks++) {
      bf16x8 ap = *(const bf16x8*)&pt[(w * 16 + (lane & 15)) * 72 + ks * 32 + (lane >> 4) * 8];
#pragma unroll
      for (int j = 0; j < 4; j++) {
        bf16x8 bv = *(const bf16x8*)&vt[(j * 16 + (lane & 15)) * 72 + ks * 32 + (lane >> 4) * 8];
        o[j] = __builtin_amdgcn_mfma_f32_16x16x32_bf16(ap, bv, o[j], 0, 0, 0);
      }
    }
  }
  // epilogue: out[b][s][h*64+d] = O / l
  const int b = bh >> 4, h = bh & 15;
#pragma unroll
  for (int r = 0; r < 4; r++) {
    int s = q0 + w * 16 + (lane >> 4) * 4 + r;
    float inv = 1.f / lrow[r];
#pragma unroll
    for (int j = 0; j < 4; j++) {
      int d = j * 16 + (lane & 15);
      out[((size_t)b * NS + s) * DM + h * HD + d] = o[j][r] * inv;
    }
  }
}

extern "C" void kernel_launch(void* const* d_in, const int* in_sizes, int n_in,
                              void* d_out, int out_size, void* d_ws, size_t ws_size,
                              hipStream_t stream) {
  // setup_inputs order: Q, V, K, wq, bq, wk, bk, wv, bv
  const float* Q  = (const float*)d_in[0];
  const float* V  = (const float*)d_in[1];
  const float* K  = (const float*)d_in[2];
  const float* wq = (const float*)d_in[3];
  const float* bq = (const float*)d_in[4];
  const float* wk = (const float*)d_in[5];
  const float* bk = (const float*)d_in[6];
  const float* wv = (const float*)d_in[7];
  const float* bv = (const float*)d_in[8];
  float* out = (float*)d_out;
  char* ws = (char*)d_ws;
  const size_t NX = (size_t)NB * NS * DIN;  // 8388608 elements
  const size_t XB = NX * 2;                 // bf16 bytes per X
  const size_t WB = (size_t)DIN * DM * 2;   // bf16 bytes per W
  u16* Xq   = (u16*)(ws);
  u16* Xk   = (u16*)(ws + XB);
  u16* Xv   = (u16*)(ws + 2 * XB);
  u16* Wtq  = (u16*)(ws + 3 * XB);
  u16* Wtk  = (u16*)(ws + 3 * XB + WB);
  u16* Wtv  = (u16*)(ws + 3 * XB + 2 * WB);
  u16* qws  = (u16*)(ws + 3 * XB + 3 * WB);
  u16* kws  = (u16*)(ws + 4 * XB + 3 * WB);
  u16* vws  = (u16*)(ws + 5 * XB + 3 * WB);
  u16* vTws = Xq;  // reuse Xq region after projections (total ws: ~106.7 MB)
  const int n4 = (int)(NX / 4);
  cvt_kernel<<<2048, 256, 0, stream>>>(Q, Xq, n4);
  cvt_kernel<<<2048, 256, 0, stream>>>(K, Xk, n4);
  cvt_kernel<<<2048, 256, 0, stream>>>(V, Xv, n4);
  wtrans_kernel<<<dim3(16, 16), 256, 0, stream>>>(wq, Wtq);
  wtrans_kernel<<<dim3(16, 16), 256, 0, stream>>>(wk, Wtk);
  wtrans_kernel<<<dim3(16, 16), 256, 0, stream>>>(wv, Wtv);
  proj_kernel<<<dim3(8, 64, 3), 256, 0, stream>>>(Xq, Xk, Xv, Wtq, Wtk, Wtv,
                                                  bq, bk, bv, qws, kws, vws);
  vtrans_kernel<<<dim3(32, 64), 256, 0, stream>>>(vws, vTws);
  attn_kernel<<<dim3(32, 64), 256, 0, stream>>>(qws, kws, vTws, out);
}